// Round 5
// baseline (454.583 us; speedup 1.0000x reference)
//
#include <hip/hip_runtime.h>

#define IMG 512
#define OUT_HW 502
#define N_IMG 64
#define XT 8                       // x-tiles of 64 cols (one wave each)
#define YT 8                       // y-tiles of 64 output rows
#define NWAVE (XT * YT * N_IMG)    // 4096 partial sums

// One wave (64 lanes) owns a 64-col x 64-row output tile. Lane = column.
// H-conv: per row, lane loads its 12-float window (unaligned, via memcpy ->
// HW supports dword-aligned dwordx4) and computes the 5 horizontal sums.
// V-conv: 5x11 register ring, static indices via 11-row unrolled body.
// No LDS maps, no barriers.
__global__ __launch_bounds__(256, 4) void ssim_main(
    const float* __restrict__ g_a, const float* __restrict__ g_b,
    const float* __restrict__ g_w, float* __restrict__ bsum)
{
  const int t = threadIdx.x;
  const int lane = t & 63;
  const int wv = t >> 6;
  const int bx = blockIdx.x;                 // 0..7
  const int ty = ((int)blockIdx.y << 2) | wv;  // 0..7
  const int y0 = ty << 6;

  const float* __restrict__ A = g_a + (size_t)blockIdx.z * (IMG * IMG);
  const float* __restrict__ B = g_b + (size_t)blockIdx.z * (IMG * IMG);

  const int x = (bx << 6) | lane;            // 0..511
  const int xc = min(x, 500);                // load base, never OOB
  const bool off1 = (x >= 501);              // lane 501: window shifted by 1
  const bool xvalid = (x <= 501);

  // exact rank-1 factor u of the Gaussian window: w[i][j] = u[i]*u[j]
  float u[11], ue[12];
  {
    const float inv = 1.0f / sqrtf(g_w[5 * 11 + 5]);
#pragma unroll
    for (int j = 0; j < 11; ++j) u[j] = g_w[j * 11 + 5] * inv;
    // per-lane pre-shifted horizontal taps (branch-free edge handling)
    ue[0] = off1 ? 0.f : u[0];
#pragma unroll
    for (int j = 1; j < 11; ++j) ue[j] = off1 ? u[j - 1] : u[j];
    ue[11] = off1 ? u[10] : 0.f;
  }

  float win[5][11];                          // V sliding window (registers)
  float score = 0.f;

  for (int i = 0; i < 7; ++i) {              // 7 x 11 = 77 rows (74 needed)
#pragma unroll
    for (int s = 0; s < 11; ++s) {
      const int r = 11 * i + s;              // ring slot == s (static)
      const int gy = min(y0 + r, IMG - 1);
      const float* pa = A + (gy << 9) + xc;
      const float* pb = B + (gy << 9) + xc;
      float a[12], b[12];
      __builtin_memcpy(a, pa, 48);
      __builtin_memcpy(b, pb, 48);

      float h0 = 0.f, h1 = 0.f, h2 = 0.f, h3 = 0.f, h4 = 0.f;
#pragma unroll
      for (int j = 0; j < 12; ++j) {
        const float ta = ue[j] * a[j], tb = ue[j] * b[j];
        h0 += ta;
        h1 += tb;
        h2 = fmaf(ta, a[j], h2);
        h3 = fmaf(tb, b[j], h3);
        h4 = fmaf(ta, b[j], h4);
      }
      win[0][s] = h0; win[1][s] = h1; win[2][s] = h2;
      win[3][s] = h3; win[4][s] = h4;

      if (i > 0 || s == 10) {                // r >= 10: a V-window is full
        float o[5];
#pragma unroll
        for (int m = 0; m < 5; ++m) {
          float acc = 0.f;
#pragma unroll
          for (int k = 0; k < 11; ++k)       // oldest row at slot (s+1)%11
            acc = fmaf(u[k], win[m][(s + 1 + k) % 11], acc);
          o[m] = acc;
        }
        const int yo = y0 + r - 10;
        const bool valid = xvalid && (yo <= OUT_HW - 1) && (r <= 73);
        const float C1 = 1e-4f, C2 = 9e-4f;
        const float mu1 = o[0], mu2 = o[1];
        const float mu1s = mu1 * mu1, mu2s = mu2 * mu2, m12 = mu1 * mu2;
        const float sig1 = o[2] - mu1s, sig2 = o[3] - mu2s, sig12 = o[4] - m12;
        const float num = (2.f * m12 + C1) * (2.f * sig12 + C2);
        const float den = (mu1s + mu2s + C1) * (sig1 + sig2 + C2);
        const float val = num * __builtin_amdgcn_rcpf(den);
        score += valid ? val : 0.f;
      }
    }
  }

  // wave-level reduction, one float per wave (no atomics, no LDS)
#pragma unroll
  for (int o = 32; o > 0; o >>= 1) score += __shfl_down(score, o);
  if (lane == 0) {
    const int widx = ((int)blockIdx.z * YT + ty) * XT + bx;
    bsum[widx] = score;
  }
}

__global__ __launch_bounds__(256) void ssim_final(
    const float* __restrict__ bsum, float* __restrict__ out)
{
  const float4* b4 = (const float4*)bsum;    // 1024 float4 = 4096 floats
  double v = 0.0;
#pragma unroll
  for (int k = 0; k < 4; ++k) {
    const float4 f = b4[k * 256 + threadIdx.x];
    v += (double)((f.x + f.y) + (f.z + f.w));
  }
#pragma unroll
  for (int off = 32; off > 0; off >>= 1) v += __shfl_down(v, off);
  __shared__ double s_red[4];
  const int wave = (int)threadIdx.x >> 6, lane = (int)threadIdx.x & 63;
  if (lane == 0) s_red[wave] = v;
  __syncthreads();
  if (threadIdx.x == 0) {
    const double total = s_red[0] + s_red[1] + s_red[2] + s_red[3];
    out[0] = (float)(total / (double)((size_t)N_IMG * OUT_HW * OUT_HW));
  }
}

extern "C" void kernel_launch(void* const* d_in, const int* in_sizes, int n_in,
                              void* d_out, int out_size, void* d_ws, size_t ws_size,
                              hipStream_t stream) {
  const float* yh = (const float*)d_in[0];
  const float* yy = (const float*)d_in[1];
  const float* w  = (const float*)d_in[2];
  float* bsum = (float*)d_ws;                // NWAVE floats = 16 KB
  float* out = (float*)d_out;

  dim3 grid(XT, YT / 4, N_IMG);              // 8 x 2 x 64 = 1024 blocks
  hipLaunchKernelGGL(ssim_main, grid, dim3(256), 0, stream, yh, yy, w, bsum);
  hipLaunchKernelGGL(ssim_final, dim3(1), dim3(256), 0, stream, bsum, out);
}

// Round 6
// 453.330 us; speedup vs baseline: 1.0028x; 1.0028x over previous
//
#include <hip/hip_runtime.h>

#define IMG 512
#define OUT_HW 502
#define N_IMG 64
#define XT 8                       // x-tiles of 64 cols (one wave each)
#define YT 8                       // y-tiles of 64 output rows
#define NWAVE (XT * YT * N_IMG)    // 4096 partial sums

// One wave (64 lanes) owns a 64-col x 64-row output tile. Lane = column.
// H-conv: per row, lane computes 5 horizontal sums from its own 12-float
// window (per-element indexed loads -> registers; each load instruction is
// lane-coalesced). V-conv: 5x11 register ring, static indices via the
// fully-unrolled 11-row body. No LDS maps, no barriers, no memcpy.
__global__ __launch_bounds__(256, 4) void ssim_main(
    const float* __restrict__ g_a, const float* __restrict__ g_b,
    const float* __restrict__ g_w, float* __restrict__ bsum)
{
  const int t = threadIdx.x;
  const int lane = t & 63;
  const int wv = t >> 6;
  const int bx = blockIdx.x;                 // 0..7
  const int ty = ((int)blockIdx.y << 2) | wv;  // 0..7
  const int y0 = ty << 6;

  const float* __restrict__ A = g_a + (size_t)blockIdx.z * (IMG * IMG);
  const float* __restrict__ B = g_b + (size_t)blockIdx.z * (IMG * IMG);

  const int x = (bx << 6) | lane;            // 0..511
  const int xc = min(x, 500);                // load base, never OOB
  const bool off1 = (x >= 501);              // lane 501: window shifted by 1
  const bool xvalid = (x <= 501);

  // exact rank-1 factor u of the Gaussian window: w[i][j] = u[i]*u[j]
  float u[11], ue[12];
  {
    const float inv = 1.0f / sqrtf(g_w[5 * 11 + 5]);
#pragma unroll
    for (int j = 0; j < 11; ++j) u[j] = g_w[j * 11 + 5] * inv;
    // per-lane pre-shifted horizontal taps (branch-free edge handling)
    ue[0] = off1 ? 0.f : u[0];
#pragma unroll
    for (int j = 1; j < 11; ++j) ue[j] = off1 ? u[j - 1] : u[j];
    ue[11] = off1 ? u[10] : 0.f;
  }

  float win[5][11];                          // V sliding window (registers)
  float score = 0.f;

  for (int i = 0; i < 7; ++i) {              // 7 x 11 = 77 rows (74 needed)
#pragma unroll
    for (int s = 0; s < 11; ++s) {
      const int r = 11 * i + s;              // ring slot == s (static)
      const int gy = min(y0 + r, IMG - 1);
      const float* pa = A + (gy << 9) + xc;
      const float* pb = B + (gy << 9) + xc;
      float a[12], b[12];
#pragma unroll
      for (int j = 0; j < 12; ++j) {         // static idx -> VGPRs (no scratch)
        a[j] = pa[j];
        b[j] = pb[j];
      }

      float h0 = 0.f, h1 = 0.f, h2 = 0.f, h3 = 0.f, h4 = 0.f;
#pragma unroll
      for (int j = 0; j < 12; ++j) {
        const float ta = ue[j] * a[j], tb = ue[j] * b[j];
        h0 += ta;
        h1 += tb;
        h2 = fmaf(ta, a[j], h2);
        h3 = fmaf(tb, b[j], h3);
        h4 = fmaf(ta, b[j], h4);
      }
      win[0][s] = h0; win[1][s] = h1; win[2][s] = h2;
      win[3][s] = h3; win[4][s] = h4;

      if (i > 0 || s == 10) {                // r >= 10: a V-window is full
        float o[5];
#pragma unroll
        for (int m = 0; m < 5; ++m) {
          float acc = 0.f;
#pragma unroll
          for (int k = 0; k < 11; ++k)       // oldest row at slot (s+1)%11
            acc = fmaf(u[k], win[m][(s + 1 + k) % 11], acc);
          o[m] = acc;
        }
        const int yo = y0 + r - 10;
        const bool valid = xvalid && (yo <= OUT_HW - 1) && (r <= 73);
        const float C1 = 1e-4f, C2 = 9e-4f;
        const float mu1 = o[0], mu2 = o[1];
        const float mu1s = mu1 * mu1, mu2s = mu2 * mu2, m12 = mu1 * mu2;
        const float sig1 = o[2] - mu1s, sig2 = o[3] - mu2s, sig12 = o[4] - m12;
        const float num = (2.f * m12 + C1) * (2.f * sig12 + C2);
        const float den = (mu1s + mu2s + C1) * (sig1 + sig2 + C2);
        const float val = num * __builtin_amdgcn_rcpf(den);
        score += valid ? val : 0.f;
      }
    }
  }

  // wave-level reduction, one float per wave (no atomics, no LDS)
#pragma unroll
  for (int o = 32; o > 0; o >>= 1) score += __shfl_down(score, o);
  if (lane == 0) {
    const int widx = ((int)blockIdx.z * YT + ty) * XT + bx;
    bsum[widx] = score;
  }
}

__global__ __launch_bounds__(256) void ssim_final(
    const float* __restrict__ bsum, float* __restrict__ out)
{
  const float4* b4 = (const float4*)bsum;    // 1024 float4 = 4096 floats
  double v = 0.0;
#pragma unroll
  for (int k = 0; k < 4; ++k) {
    const float4 f = b4[k * 256 + threadIdx.x];
    v += (double)((f.x + f.y) + (f.z + f.w));
  }
#pragma unroll
  for (int off = 32; off > 0; off >>= 1) v += __shfl_down(v, off);
  __shared__ double s_red[4];
  const int wave = (int)threadIdx.x >> 6, lane = (int)threadIdx.x & 63;
  if (lane == 0) s_red[wave] = v;
  __syncthreads();
  if (threadIdx.x == 0) {
    const double total = s_red[0] + s_red[1] + s_red[2] + s_red[3];
    out[0] = (float)(total / (double)((size_t)N_IMG * OUT_HW * OUT_HW));
  }
}

extern "C" void kernel_launch(void* const* d_in, const int* in_sizes, int n_in,
                              void* d_out, int out_size, void* d_ws, size_t ws_size,
                              hipStream_t stream) {
  const float* yh = (const float*)d_in[0];
  const float* yy = (const float*)d_in[1];
  const float* w  = (const float*)d_in[2];
  float* bsum = (float*)d_ws;                // NWAVE floats = 16 KB
  float* out = (float*)d_out;

  dim3 grid(XT, YT / 4, N_IMG);              // 8 x 2 x 64 = 1024 blocks
  hipLaunchKernelGGL(ssim_main, grid, dim3(256), 0, stream, yh, yy, w, bsum);
  hipLaunchKernelGGL(ssim_final, dim3(1), dim3(256), 0, stream, bsum, out);
}

// Round 7
// 211.883 us; speedup vs baseline: 2.1454x; 2.1395x over previous
//
#include <hip/hip_runtime.h>

#define IMG 512
#define OUT_HW 502
#define N_IMG 64
#define XT 8                        // x-tiles: 64 cols each (lane = column)
#define YT 6                        // y-tiles: 89 output rows each
#define OROWS 89                    // outputs per wave (9*11 input rows - 10)
#define NWAVE (XT * YT * N_IMG)     // 3072 partial sums

// One wave (= one 64-thread block) owns a 64-col x 89-row output tile.
// Lane = column. H-conv: 11 scalar loads per image per row from base
// min(x,501) -- that is exactly the 11-tap window for every valid output
// column, no shifted taps needed. V-conv: 5x11 register ring with static
// indices (11-row unrolled inner loop). No LDS, no barriers.
__global__ __launch_bounds__(64, 2) void ssim_main(
    const float* __restrict__ g_a, const float* __restrict__ g_b,
    const float* __restrict__ g_w, float* __restrict__ bsum)
{
  const int lane = threadIdx.x;              // 0..63
  const int xt = blockIdx.x;                 // 0..7
  const int yt = blockIdx.y;                 // 0..5
  const int y0 = yt * OROWS;

  const float* __restrict__ A = g_a + (size_t)blockIdx.z * (IMG * IMG);
  const float* __restrict__ B = g_b + (size_t)blockIdx.z * (IMG * IMG);

  const int x = (xt << 6) | lane;            // 0..511
  const int xb = min(x, OUT_HW - 1);         // load base; max col 501+10=511
  const bool xvalid = (x <= OUT_HW - 1);

  // exact rank-1 factor u of the Gaussian window: w[i][j] = u[i]*u[j]
  float u[11];
  {
    const float inv = 1.0f / sqrtf(g_w[5 * 11 + 5]);
#pragma unroll
    for (int j = 0; j < 11; ++j) u[j] = g_w[j * 11 + 5] * inv;
  }

  float win[5][11];                          // V sliding window (registers)
  float score = 0.f;

  for (int i = 0; i < 9; ++i) {              // 9 x 11 = 99 input rows
#pragma unroll
    for (int s = 0; s < 11; ++s) {
      const int r = 11 * i + s;              // ring slot == s (static)
      const int gy = min(y0 + r, IMG - 1);
      const float* pa = A + (gy << 9) + xb;
      const float* pb = B + (gy << 9) + xb;
      float a[11], b[11];
#pragma unroll
      for (int j = 0; j < 11; ++j) {         // static idx -> VGPRs
        a[j] = pa[j];
        b[j] = pb[j];
      }

      float h0 = 0.f, h1 = 0.f, h2 = 0.f, h3 = 0.f, h4 = 0.f;
#pragma unroll
      for (int j = 0; j < 11; ++j) {
        const float ta = u[j] * a[j], tb = u[j] * b[j];
        h0 += ta;
        h1 += tb;
        h2 = fmaf(ta, a[j], h2);
        h3 = fmaf(tb, b[j], h3);
        h4 = fmaf(ta, b[j], h4);
      }
      win[0][s] = h0; win[1][s] = h1; win[2][s] = h2;
      win[3][s] = h3; win[4][s] = h4;

      if (i > 0 || s == 10) {                // r >= 10: a V-window is full
        float o[5];
#pragma unroll
        for (int m = 0; m < 5; ++m) {
          float acc = 0.f;
#pragma unroll
          for (int k = 0; k < 11; ++k)       // oldest row at slot (s+1)%11
            acc = fmaf(u[k], win[m][(s + 1 + k) % 11], acc);
          o[m] = acc;
        }
        const int yo = y0 + r - 10;
        const bool valid = xvalid && (yo < OUT_HW);
        const float C1 = 1e-4f, C2 = 9e-4f;
        const float mu1 = o[0], mu2 = o[1];
        const float mu1s = mu1 * mu1, mu2s = mu2 * mu2, m12 = mu1 * mu2;
        const float sig1 = o[2] - mu1s, sig2 = o[3] - mu2s, sig12 = o[4] - m12;
        const float num = (2.f * m12 + C1) * (2.f * sig12 + C2);
        const float den = (mu1s + mu2s + C1) * (sig1 + sig2 + C2);
        const float val = num * __builtin_amdgcn_rcpf(den);
        score += valid ? val : 0.f;
      }
    }
  }

  // wave-level reduction, one float per wave
#pragma unroll
  for (int o = 32; o > 0; o >>= 1) score += __shfl_down(score, o);
  if (lane == 0) {
    const int widx = ((int)blockIdx.z * YT + yt) * XT + xt;
    bsum[widx] = score;
  }
}

__global__ __launch_bounds__(256) void ssim_final(
    const float* __restrict__ bsum, float* __restrict__ out)
{
  const float4* b4 = (const float4*)bsum;    // 768 float4 = 3072 floats
  double v = 0.0;
#pragma unroll
  for (int k = 0; k < 3; ++k) {
    const float4 f = b4[k * 256 + threadIdx.x];
    v += (double)((f.x + f.y) + (f.z + f.w));
  }
#pragma unroll
  for (int off = 32; off > 0; off >>= 1) v += __shfl_down(v, off);
  __shared__ double s_red[4];
  const int wave = (int)threadIdx.x >> 6, lane = (int)threadIdx.x & 63;
  if (lane == 0) s_red[wave] = v;
  __syncthreads();
  if (threadIdx.x == 0) {
    const double total = s_red[0] + s_red[1] + s_red[2] + s_red[3];
    out[0] = (float)(total / (double)((size_t)N_IMG * OUT_HW * OUT_HW));
  }
}

extern "C" void kernel_launch(void* const* d_in, const int* in_sizes, int n_in,
                              void* d_out, int out_size, void* d_ws, size_t ws_size,
                              hipStream_t stream) {
  const float* yh = (const float*)d_in[0];
  const float* yy = (const float*)d_in[1];
  const float* w  = (const float*)d_in[2];
  float* bsum = (float*)d_ws;                // NWAVE floats = 12 KB
  float* out = (float*)d_out;

  dim3 grid(XT, YT, N_IMG);                  // 3072 one-wave blocks
  hipLaunchKernelGGL(ssim_main, grid, dim3(64), 0, stream, yh, yy, w, bsum);
  hipLaunchKernelGGL(ssim_final, dim3(1), dim3(256), 0, stream, bsum, out);
}